// Round 12
// baseline (104.385 us; speedup 1.0000x reference)
//
#include <hip/hip_runtime.h>

#define NROWS 8192
#define DIM   1024
#define EPSF  1e-8f

typedef __attribute__((ext_vector_type(4))) float f32x4;
typedef __attribute__((ext_vector_type(4))) int   i32x4;
typedef __attribute__((ext_vector_type(8))) int   i32x8;

typedef __attribute__((address_space(1))) void g_void;
typedef __attribute__((address_space(3))) void l_void;

#define SCALE1 0x7F7F7F7F   // e8m0 byte 0x7F = 2^0 = 1.0 in every opsel slot

__device__ __forceinline__ void async_copy16(void* lds, const void* g) {
  __builtin_amdgcn_global_load_lds((g_void*)const_cast<void*>(g), (l_void*)lds, 16, 0, 0);
}

__device__ __forceinline__ unsigned encf(float f) {
  const unsigned bits = __float_as_uint(f);
  return (bits & 0x80000000u) ? ~bits : (bits | 0x80000000u);
}

template<int N> __device__ __forceinline__ void vmwait() {
  if constexpr (N == 8)      asm volatile("s_waitcnt vmcnt(8)" ::: "memory");
  else                       asm volatile("s_waitcnt vmcnt(0)" ::: "memory");
}
__device__ __forceinline__ void barf() {
  __builtin_amdgcn_s_barrier();
  asm volatile("" ::: "memory");
}

// ---------------- Kernel A: row L2-normalize, quantize to fp8 e4m3, init maxenc ----------------
extern "C" __global__ __launch_bounds__(256)
void koleo_norm(const float* __restrict__ in, int* __restrict__ xq,
                unsigned* __restrict__ maxenc) {
  const int row = blockIdx.x;
  const int tid = threadIdx.x;
  const float4 v = reinterpret_cast<const float4*>(in + (size_t)row * DIM)[tid];
  float ss = v.x * v.x + v.y * v.y + v.z * v.z + v.w * v.w;
#pragma unroll
  for (int off = 32; off > 0; off >>= 1) ss += __shfl_down(ss, off);
  __shared__ float wsum[4];
  if ((tid & 63) == 0) wsum[tid >> 6] = ss;
  __syncthreads();
  const float total = wsum[0] + wsum[1] + wsum[2] + wsum[3];
  const float scale = 1.0f / (sqrtf(total) + EPSF);
  int p = __builtin_amdgcn_cvt_pk_fp8_f32(v.x * scale, v.y * scale, 0, false);
  p = __builtin_amdgcn_cvt_pk_fp8_f32(v.z * scale, v.w * scale, p, true);
  xq[row * 256 + tid] = p;
  if (row < NROWS / 256) maxenc[row * 256 + tid] = 0u;  // enc(any real dot) > 0
}

// -------- Kernel B: upper-triangle Gram-max, 128x128 fp8, MX 16x16x128 MFMA, 2 blocks/CU --------
#define BM 128
#define NT  (NROWS / BM)            // 64 tiles per dim
#define NBLK (NT * (NT + 1) / 2)    // 2080 upper-triangle blocks
#define NKT 8                       // 8 K-tiles of 128 fp8 bytes

// stage one 16KB chunk = 128 rows x 128B (one operand, one K-tile), 256 threads.
// XOR-swizzled SOURCE, linear gload_lds dest (R5/R9/R11-proven):
// LDS[row][c] = global[row][c ^ ((row&7)<<4)]
__device__ __forceinline__ void stage_chunk(char* dst, const char* gbase, int kt, int tid) {
#pragma unroll
  for (int l = 0; l < 4; ++l) {
    const int o  = l * 4096 + tid * 16;
    const int so = o ^ (((o >> 7) & 7) << 4);
    async_copy16(dst + o, gbase + (size_t)(so >> 7) * 1024 + kt * 128 + (so & 127));
  }
}

// 16x16x128 f8f6f4 operand: lane (lr, lg) holds rows lr, k = lg*32..+31 (8 VGPRs).
// Two b128 reads per frag at cols lg*32, lg*32+16, each XOR'd by (row&7)<<4.
#define READ_FRAG(dstv, base)                                                         \
  {                                                                                   \
    i32x4 v0 = *(const i32x4*)((base) + ((lg * 32) ^ xr));                            \
    i32x4 v1 = *(const i32x4*)((base) + ((lg * 32 + 16) ^ xr));                       \
    dstv[0] = v0.x; dstv[1] = v0.y; dstv[2] = v0.z; dstv[3] = v0.w;                   \
    dstv[4] = v1.x; dstv[5] = v1.y; dstv[6] = v1.z; dstv[7] = v1.w;                   \
  }
#define READ_ALL()                                                                    \
  {                                                                                   \
    _Pragma("unroll")                                                                 \
    for (int mm = 0; mm < 4; ++mm)                                                    \
      READ_FRAG(aF[mm], Lc + (wr * 64 + mm * 16 + lr) * 128);                         \
    _Pragma("unroll")                                                                 \
    for (int nn = 0; nn < 4; ++nn)                                                    \
      READ_FRAG(bF[nn], Lc + 16384 + (wc * 64 + nn * 16 + lr) * 128);                 \
  }
#define MFMAALL()                                                                     \
  {                                                                                   \
    _Pragma("unroll")                                                                 \
    for (int mm = 0; mm < 4; ++mm)                                                    \
      _Pragma("unroll")                                                               \
      for (int nn = 0; nn < 4; ++nn)                                                  \
        acc[mm][nn] = __builtin_amdgcn_mfma_scale_f32_16x16x128_f8f6f4(               \
            aF[mm], bF[nn], acc[mm][nn], 0, 0, 0, SCALE1, 0, SCALE1);                 \
  }

// Per K-tile t (buffer Lc): read all frags (16 b128); BAR (all tile-t reads precede
// stores); stage tile t+2 -> Lc (8 loads); vmcnt(8) = tile t+1 complete, t+2's 8 in
// flight; BAR; 16 MFMA. Same wait arithmetic as validated R7/R9/R11.
template<bool ST, int V>
__device__ __forceinline__ void ktile(int t, char* Lc,
    const char* gA, const char* gB, int tid, int lane, int wr, int wc,
    i32x8 (&aF)[4], i32x8 (&bF)[4], f32x4 (&acc)[4][4]) {
  const int lr = lane & 15, lg = lane >> 4;
  const int xr = (lane & 7) << 4;
  READ_ALL();
  barf();                                   // all waves' tile-t reads precede stages
  if constexpr (ST) {
    stage_chunk(Lc,         gA, t + 2, tid);
    stage_chunk(Lc + 16384, gB, t + 2, tid);
  }
  if constexpr (V >= 0) vmwait<V>();        // tile t+1 data complete
  barf();                                   // fence before next tile's reads
  __builtin_amdgcn_s_setprio(1); MFMAALL(); __builtin_amdgcn_s_setprio(0);
}

extern "C" __global__ __launch_bounds__(256)
void koleo_grammax(const char* __restrict__ xq, unsigned* __restrict__ maxenc) {
  __shared__ char lds[65536];   // 2 dbuf x (A 16KB + B 16KB) -> 2 blocks/CU

  const int tid  = threadIdx.x;
  const int lane = tid & 63;
  const int wid  = tid >> 6;
  const int wr   = wid >> 1;     // 0..1: rows wr*64..+63
  const int wc   = wid & 1;      // 0..1: cols wc*64..+63
  const int lr   = lane & 15;
  const int lg   = lane >> 4;

  // XCD-aware bijective swizzle (2080 % 8 == 0)
  const int bid = (blockIdx.x % 8) * (NBLK / 8) + blockIdx.x / 8;
  // upper-triangle decode (ti <= tj), NT=64 (R1/R11-proven)
  int ti = (int)((2.0f * NT + 1.0f -
                  sqrtf((float)((2 * NT + 1) * (2 * NT + 1) - 8 * bid))) * 0.5f);
  while ((ti + 1) * NT - ((ti + 1) * ti) / 2 <= bid) ++ti;
  while (ti * NT - (ti * (ti - 1)) / 2 > bid) --ti;
  const int tj = ti + (bid - (ti * NT - (ti * (ti - 1)) / 2));

  const int rowBase = ti * BM;
  const int colBase = tj * BM;
  const bool diag = (ti == tj);

  const char* gA = xq + (size_t)rowBase * 1024;
  const char* gB = xq + (size_t)colBase * 1024;
  char* L0 = lds;
  char* L1 = lds + 32768;

  f32x4 acc[4][4] = {};
  i32x8 aF[4];
  i32x8 bF[4];

  // prologue: tile 0 -> L0 (8 loads), tile 1 -> L1 (8 loads)
  stage_chunk(L0,         gA, 0, tid);
  stage_chunk(L0 + 16384, gB, 0, tid);
  stage_chunk(L1,         gA, 1, tid);
  stage_chunk(L1 + 16384, gB, 1, tid);
  vmwait<8>();   // tile 0 complete; tile 1's 8 loads in flight
  barf();

#pragma unroll 1
  for (int t2 = 0; t2 < 6; t2 += 2) {
    ktile<true, 8>(t2,     L0, gA, gB, tid, lane, wr, wc, aF, bF, acc);
    ktile<true, 8>(t2 + 1, L1, gA, gB, tid, lane, wr, wc, aF, bF, acc);
  }
  ktile<false, 0>(6, L0, gA, gB, tid, lane, wr, wc, aF, bF, acc);   // drain tile-7 loads
  ktile<false, -1>(7, L1, gA, gB, tid, lane, wr, wc, aF, bF, acc);

  // ---- epilogue: per-row / per-col max with diagonal mask (16x16 C/D layout, R9/R11-proven) ----
  __syncthreads();
  unsigned* smaxr = (unsigned*)lds;           // [128]
  unsigned* smaxc = (unsigned*)(lds + 512);   // [128]
  if (tid < 128) { smaxr[tid] = 0u; smaxc[tid] = 0u; }
  __syncthreads();

#pragma unroll
  for (int m = 0; m < 4; ++m) {
#pragma unroll
    for (int rr = 0; rr < 4; ++rr) {
      const int lrow = wr * 64 + m * 16 + lg * 4 + rr;  // C/D: row=(lane>>4)*4+reg
      const int grow = rowBase + lrow;
      float mx = -2.0f;
#pragma unroll
      for (int n = 0; n < 4; ++n) {
        float v = acc[m][n][rr];
        const int gcol = colBase + wc * 64 + n * 16 + lr;  // C/D: col=lane&15
        if (grow == gcol) v = -2.0f;                        // mask self-similarity
        mx = fmaxf(mx, v);
      }
#pragma unroll
      for (int off = 1; off < 16; off <<= 1) mx = fmaxf(mx, __shfl_xor(mx, off));
      if (lr == 0) atomicMax(&smaxr[lrow], encf(mx));
    }
  }
  if (!diag) {  // symmetric fold: col j's max over this block's rows
#pragma unroll
    for (int n = 0; n < 4; ++n) {
      const int lcol = wc * 64 + n * 16 + lr;
      float mx = -2.0f;
#pragma unroll
      for (int m = 0; m < 4; ++m)
#pragma unroll
        for (int rr = 0; rr < 4; ++rr) mx = fmaxf(mx, acc[m][n][rr]);
      mx = fmaxf(mx, __shfl_xor(mx, 16));
      mx = fmaxf(mx, __shfl_xor(mx, 32));
      if (lg == 0) atomicMax(&smaxc[lcol], encf(mx));
    }
  }
  __syncthreads();
  if (tid < 128) {
    atomicMax(&maxenc[rowBase + tid], smaxr[tid]);
    if (!diag) atomicMax(&maxenc[colBase + tid], smaxc[tid]);
  }
}

// ---------------- Kernel C: loss reduction ----------------
extern "C" __global__ __launch_bounds__(1024)
void koleo_loss(const unsigned* __restrict__ maxenc, float* __restrict__ out) {
  const int tid = threadIdx.x;
  float sum = 0.0f;
#pragma unroll
  for (int i = tid; i < NROWS; i += 1024) {
    const unsigned u    = maxenc[i];
    const unsigned bits = (u & 0x80000000u) ? (u & 0x7FFFFFFFu) : ~u;
    const float m = __uint_as_float(bits);
    const float d = sqrtf(fmaxf(2.0f - 2.0f * m, 0.0f)) + EPSF;  // ||x_i - x_nn|| + eps
    sum += logf(d + EPSF);
  }
#pragma unroll
  for (int off = 32; off > 0; off >>= 1) sum += __shfl_down(sum, off);
  __shared__ float wsum[16];
  if ((tid & 63) == 0) wsum[tid >> 6] = sum;
  __syncthreads();
  if (tid == 0) {
    float t = 0.0f;
#pragma unroll
    for (int w = 0; w < 16; ++w) t += wsum[w];
    out[0] = -t / (float)NROWS;
  }
}

extern "C" void kernel_launch(void* const* d_in, const int* in_sizes, int n_in,
                              void* d_out, int out_size, void* d_ws, size_t ws_size,
                              hipStream_t stream) {
  const float* in = (const float*)d_in[0];
  char* xq         = (char*)d_ws;                                        // 8 MB fp8 x
  unsigned* maxenc = (unsigned*)((char*)d_ws + (size_t)NROWS * DIM);     // 32 KB
  float* out = (float*)d_out;

  hipLaunchKernelGGL(koleo_norm,    dim3(NROWS), dim3(256),  0, stream, in, (int*)xq, maxenc);
  hipLaunchKernelGGL(koleo_grammax, dim3(NBLK),  dim3(256),  0, stream, xq, maxenc);
  hipLaunchKernelGGL(koleo_loss,    dim3(1),     dim3(1024), 0, stream, maxenc, out);
}

// Round 13
// 95.718 us; speedup vs baseline: 1.0905x; 1.0905x over previous
//
#include <hip/hip_runtime.h>

#define NROWS 8192
#define DIM   1024
#define EPSF  1e-8f

typedef __attribute__((ext_vector_type(4))) float f32x4;

typedef __attribute__((address_space(1))) void g_void;
typedef __attribute__((address_space(3))) void l_void;

__device__ __forceinline__ void async_copy16(void* lds, const void* g) {
  __builtin_amdgcn_global_load_lds((g_void*)const_cast<void*>(g), (l_void*)lds, 16, 0, 0);
}

__device__ __forceinline__ unsigned encf(float f) {
  const unsigned bits = __float_as_uint(f);
  return (bits & 0x80000000u) ? ~bits : (bits | 0x80000000u);
}

__device__ __forceinline__ void vmwait0() {
  asm volatile("s_waitcnt vmcnt(0)" ::: "memory");
}
__device__ __forceinline__ void barf() {
  __builtin_amdgcn_s_barrier();
  asm volatile("" ::: "memory");
}

// ---------------- Kernel A: row L2-normalize, quantize to fp8 e4m3, init maxenc ----------------
// (identical to R9/R11 — proven absmax 0.0)
extern "C" __global__ __launch_bounds__(256)
void koleo_norm(const float* __restrict__ in, int* __restrict__ xq,
                unsigned* __restrict__ maxenc) {
  const int row = blockIdx.x;
  const int tid = threadIdx.x;
  const float4 v = reinterpret_cast<const float4*>(in + (size_t)row * DIM)[tid];
  float ss = v.x * v.x + v.y * v.y + v.z * v.z + v.w * v.w;
#pragma unroll
  for (int off = 32; off > 0; off >>= 1) ss += __shfl_down(ss, off);
  __shared__ float wsum[4];
  if ((tid & 63) == 0) wsum[tid >> 6] = ss;
  __syncthreads();
  const float total = wsum[0] + wsum[1] + wsum[2] + wsum[3];
  const float scale = 1.0f / (sqrtf(total) + EPSF);
  int p = __builtin_amdgcn_cvt_pk_fp8_f32(v.x * scale, v.y * scale, 0, false);
  p = __builtin_amdgcn_cvt_pk_fp8_f32(v.z * scale, v.w * scale, p, true);
  xq[row * 256 + tid] = p;
  if (row < NROWS / 256) maxenc[row * 256 + tid] = 0u;  // enc(any real dot) > 0
}

// -------- Kernel B: upper-triangle Gram-max, 128x128 fp8, single 32KB buffer, 5 blocks/CU --------
#define BM 128
#define NT  (NROWS / BM)            // 64 tiles per dim
#define NBLK (NT * (NT + 1) / 2)    // 2080 upper-triangle blocks
#define NKT 8                       // 8 K-tiles of 128 fp8 bytes

// stage one 16KB chunk = 128 rows x 128B (one operand, one K-tile), 256 threads.
// XOR-swizzled SOURCE, linear gload_lds dest (R5/R9/R11-proven):
// LDS[row][c] = global[row][c ^ ((row&7)<<4)]
__device__ __forceinline__ void stage_chunk(char* dst, const char* gbase, int kt, int tid) {
#pragma unroll
  for (int l = 0; l < 4; ++l) {
    const int o  = l * 4096 + tid * 16;
    const int so = o ^ (((o >> 7) & 7) << 4);
    async_copy16(dst + o, gbase + (size_t)(so >> 7) * 1024 + kt * 128 + (so & 127));
  }
}

// fp8 16x16x32 fragment reads (R9/R11-proven): lane (lr,lg) kstep s -> 8 bytes at
// row*128 + s*32 + lg*8, XOR'd by (row&7)<<4 == xr (involution cancels the stage swizzle).
#define READ_AB(S0)                                                                   \
  {                                                                                   \
    _Pragma("unroll")                                                                 \
    for (int mm = 0; mm < 4; ++mm)                                                    \
      _Pragma("unroll")                                                               \
      for (int s = 0; s < 2; ++s)                                                     \
        aS[mm][s] = *(const long*)(Lc +                                               \
            (((wr * 64 + mm * 16 + lr) * 128 + ((S0) + s) * 32 + lg * 8) ^ xr));      \
    _Pragma("unroll")                                                                 \
    for (int nn = 0; nn < 4; ++nn)                                                    \
      _Pragma("unroll")                                                               \
      for (int s = 0; s < 2; ++s)                                                     \
        bS[nn][s] = *(const long*)(Lc + 16384 +                                       \
            (((wc * 64 + nn * 16 + lr) * 128 + ((S0) + s) * 32 + lg * 8) ^ xr));      \
  }
#define MFMA2()                                                                       \
  {                                                                                   \
    _Pragma("unroll")                                                                 \
    for (int s = 0; s < 2; ++s)                                                       \
      _Pragma("unroll")                                                               \
      for (int mm = 0; mm < 4; ++mm)                                                  \
        _Pragma("unroll")                                                             \
        for (int nn = 0; nn < 4; ++nn)                                                \
          acc[mm][nn] = __builtin_amdgcn_mfma_f32_16x16x32_fp8_fp8(                   \
              aS[mm][s], bS[nn][s], acc[mm][nn], 0, 0, 0);                            \
  }

extern "C" __global__ __launch_bounds__(256)
void koleo_grammax(const char* __restrict__ xq, unsigned* __restrict__ maxenc) {
  __shared__ char lds[32768];   // single buffer (A 16KB + B 16KB) -> up to 5 blocks/CU

  const int tid  = threadIdx.x;
  const int lane = tid & 63;
  const int wid  = tid >> 6;
  const int wr   = wid >> 1;     // 0..1: rows wr*64..+63
  const int wc   = wid & 1;      // 0..1: cols wc*64..+63
  const int lr   = lane & 15;
  const int lg   = lane >> 4;
  const int xr   = (lane & 7) << 4;

  // XCD-aware bijective swizzle (2080 % 8 == 0)
  const int bid = (blockIdx.x % 8) * (NBLK / 8) + blockIdx.x / 8;
  // upper-triangle decode (ti <= tj), NT=64 (R1/R11-proven)
  int ti = (int)((2.0f * NT + 1.0f -
                  sqrtf((float)((2 * NT + 1) * (2 * NT + 1) - 8 * bid))) * 0.5f);
  while ((ti + 1) * NT - ((ti + 1) * ti) / 2 <= bid) ++ti;
  while (ti * NT - (ti * (ti - 1)) / 2 > bid) --ti;
  const int tj = ti + (bid - (ti * NT - (ti * (ti - 1)) / 2));

  const int rowBase = ti * BM;
  const int colBase = tj * BM;
  const bool diag = (ti == tj);

  const char* gA = xq + (size_t)rowBase * 1024;
  const char* gB = xq + (size_t)colBase * 1024;
  char* Lc = lds;

  f32x4 acc[4][4] = {};
  long  aS[4][2];
  long  bS[4][2];

  // prologue: tile 0 -> buffer, full drain
  stage_chunk(Lc,         gA, 0, tid);
  stage_chunk(Lc + 16384, gB, 0, tid);
  vmwait0();
  barf();

  // Per K-tile t<7: {reads s0-1; MFMA; reads s2-3; BAR (all tile-t reads issued);
  // stage t+1 into SAME buffer; vmcnt(0); BAR; MFMA}. The drain is hidden by
  // 4-5 co-resident blocks per CU (m114 TLP). Same read-vs-DMA race profile as
  // the validated R7/R9/R11 kernels.
#pragma unroll 1
  for (int t = 0; t < 7; ++t) {
    READ_AB(0);
    __builtin_amdgcn_s_setprio(1); MFMA2(); __builtin_amdgcn_s_setprio(0);
    READ_AB(2);
    barf();                                   // all waves' tile-t reads precede stages
    stage_chunk(Lc,         gA, t + 1, tid);
    stage_chunk(Lc + 16384, gB, t + 1, tid);
    vmwait0();                                // tile t+1 complete
    barf();                                   // fence before next tile's reads
    __builtin_amdgcn_s_setprio(1); MFMA2(); __builtin_amdgcn_s_setprio(0);
  }
  // t=7: no staging, no barriers needed (all waves synced at t=6's drain)
  {
    READ_AB(0);
    __builtin_amdgcn_s_setprio(1); MFMA2(); __builtin_amdgcn_s_setprio(0);
    READ_AB(2);
    __builtin_amdgcn_s_setprio(1); MFMA2(); __builtin_amdgcn_s_setprio(0);
  }

  // ---- epilogue: per-row / per-col max with diagonal mask (16x16 C/D layout, proven) ----
  __syncthreads();
  unsigned* smaxr = (unsigned*)lds;           // [128]
  unsigned* smaxc = (unsigned*)(lds + 512);   // [128]
  if (tid < 128) { smaxr[tid] = 0u; smaxc[tid] = 0u; }
  __syncthreads();

#pragma unroll
  for (int m = 0; m < 4; ++m) {
#pragma unroll
    for (int rr = 0; rr < 4; ++rr) {
      const int lrow = wr * 64 + m * 16 + lg * 4 + rr;  // C/D: row=(lane>>4)*4+reg
      const int grow = rowBase + lrow;
      float mx = -2.0f;
#pragma unroll
      for (int n = 0; n < 4; ++n) {
        float v = acc[m][n][rr];
        const int gcol = colBase + wc * 64 + n * 16 + lr;  // C/D: col=lane&15
        if (grow == gcol) v = -2.0f;                        // mask self-similarity
        mx = fmaxf(mx, v);
      }
#pragma unroll
      for (int off = 1; off < 16; off <<= 1) mx = fmaxf(mx, __shfl_xor(mx, off));
      if (lr == 0) atomicMax(&smaxr[lrow], encf(mx));
    }
  }
  if (!diag) {  // symmetric fold: col j's max over this block's rows
#pragma unroll
    for (int n = 0; n < 4; ++n) {
      const int lcol = wc * 64 + n * 16 + lr;
      float mx = -2.0f;
#pragma unroll
      for (int m = 0; m < 4; ++m)
#pragma unroll
        for (int rr = 0; rr < 4; ++rr) mx = fmaxf(mx, acc[m][n][rr]);
      mx = fmaxf(mx, __shfl_xor(mx, 16));
      mx = fmaxf(mx, __shfl_xor(mx, 32));
      if (lg == 0) atomicMax(&smaxc[lcol], encf(mx));
    }
  }
  __syncthreads();
  if (tid < 128) {
    atomicMax(&maxenc[rowBase + tid], smaxr[tid]);
    if (!diag) atomicMax(&maxenc[colBase + tid], smaxc[tid]);
  }
}

// ---------------- Kernel C: loss reduction ----------------
extern "C" __global__ __launch_bounds__(1024)
void koleo_loss(const unsigned* __restrict__ maxenc, float* __restrict__ out) {
  const int tid = threadIdx.x;
  float sum = 0.0f;
#pragma unroll
  for (int i = tid; i < NROWS; i += 1024) {
    const unsigned u    = maxenc[i];
    const unsigned bits = (u & 0x80000000u) ? (u & 0x7FFFFFFFu) : ~u;
    const float m = __uint_as_float(bits);
    const float d = sqrtf(fmaxf(2.0f - 2.0f * m, 0.0f)) + EPSF;  // ||x_i - x_nn|| + eps
    sum += logf(d + EPSF);
  }
#pragma unroll
  for (int off = 32; off > 0; off >>= 1) sum += __shfl_down(sum, off);
  __shared__ float wsum[16];
  if ((tid & 63) == 0) wsum[tid >> 6] = sum;
  __syncthreads();
  if (tid == 0) {
    float t = 0.0f;
#pragma unroll
    for (int w = 0; w < 16; ++w) t += wsum[w];
    out[0] = -t / (float)NROWS;
  }
}

extern "C" void kernel_launch(void* const* d_in, const int* in_sizes, int n_in,
                              void* d_out, int out_size, void* d_ws, size_t ws_size,
                              hipStream_t stream) {
  const float* in = (const float*)d_in[0];
  char* xq         = (char*)d_ws;                                        // 8 MB fp8 x
  unsigned* maxenc = (unsigned*)((char*)d_ws + (size_t)NROWS * DIM);     // 32 KB
  float* out = (float*)d_out;

  hipLaunchKernelGGL(koleo_norm,    dim3(NROWS), dim3(256),  0, stream, in, (int*)xq, maxenc);
  hipLaunchKernelGGL(koleo_grammax, dim3(NBLK),  dim3(256),  0, stream, xq, maxenc);
  hipLaunchKernelGGL(koleo_loss,    dim3(1),     dim3(1024), 0, stream, maxenc, out);
}

// Round 14
// 89.501 us; speedup vs baseline: 1.1663x; 1.0695x over previous
//
#include <hip/hip_runtime.h>

#define NROWS 8192
#define DIM   1024
#define EPSF  1e-8f

typedef __attribute__((ext_vector_type(4))) float f32x4;

typedef __attribute__((address_space(1))) void g_void;
typedef __attribute__((address_space(3))) void l_void;

__device__ __forceinline__ void async_copy16(void* lds, const void* g) {
  __builtin_amdgcn_global_load_lds((g_void*)const_cast<void*>(g), (l_void*)lds, 16, 0, 0);
}

__device__ __forceinline__ unsigned encf(float f) {
  const unsigned bits = __float_as_uint(f);
  return (bits & 0x80000000u) ? ~bits : (bits | 0x80000000u);
}

template<int N> __device__ __forceinline__ void vmwait() {
  if constexpr (N == 4) asm volatile("s_waitcnt vmcnt(4)" ::: "memory");
  else                  asm volatile("s_waitcnt vmcnt(0)" ::: "memory");
}
__device__ __forceinline__ void barf() {
  __builtin_amdgcn_s_barrier();
  asm volatile("" ::: "memory");
}

// ---------------- Kernel A: row L2-normalize, quantize to fp8 e4m3, init maxenc ----------------
// (identical to R9/R11 — proven absmax 0.0)
extern "C" __global__ __launch_bounds__(256)
void koleo_norm(const float* __restrict__ in, int* __restrict__ xq,
                unsigned* __restrict__ maxenc) {
  const int row = blockIdx.x;
  const int tid = threadIdx.x;
  const float4 v = reinterpret_cast<const float4*>(in + (size_t)row * DIM)[tid];
  float ss = v.x * v.x + v.y * v.y + v.z * v.z + v.w * v.w;
#pragma unroll
  for (int off = 32; off > 0; off >>= 1) ss += __shfl_down(ss, off);
  __shared__ float wsum[4];
  if ((tid & 63) == 0) wsum[tid >> 6] = ss;
  __syncthreads();
  const float total = wsum[0] + wsum[1] + wsum[2] + wsum[3];
  const float scale = 1.0f / (sqrtf(total) + EPSF);
  int p = __builtin_amdgcn_cvt_pk_fp8_f32(v.x * scale, v.y * scale, 0, false);
  p = __builtin_amdgcn_cvt_pk_fp8_f32(v.z * scale, v.w * scale, p, true);
  xq[row * 256 + tid] = p;
  if (row < NROWS / 256) maxenc[row * 256 + tid] = 0u;  // enc(any real dot) > 0
}

// ---- Kernel B: upper-triangle Gram-max, 128x128 fp8, 48KB LDS (A 1-buf + B dbuf), 3 blocks/CU ----
#define BM 128
#define NT  (NROWS / BM)            // 64 tiles per dim
#define NBLK (NT * (NT + 1) / 2)    // 2080 upper-triangle blocks
#define NKT 8                       // 8 K-tiles of 128 fp8 bytes

// stage one 16KB chunk = 128 rows x 128B, XOR-swizzled SOURCE, linear dest (proven):
// LDS[row][c] = global[row][c ^ ((row&7)<<4)]
__device__ __forceinline__ void stage_chunk(char* dst, const char* gbase, int kt, int tid) {
#pragma unroll
  for (int l = 0; l < 4; ++l) {
    const int o  = l * 4096 + tid * 16;
    const int so = o ^ (((o >> 7) & 7) << 4);
    async_copy16(dst + o, gbase + (size_t)(so >> 7) * 1024 + kt * 128 + (so & 127));
  }
}

// fp8 16x16x32 fragment reads (R9/R11-proven layout), A from La, B from Lb
#define READ_AB(S0)                                                                   \
  {                                                                                   \
    _Pragma("unroll")                                                                 \
    for (int mm = 0; mm < 4; ++mm)                                                    \
      _Pragma("unroll")                                                               \
      for (int s = 0; s < 2; ++s)                                                     \
        aS[mm][s] = *(const long*)(La +                                               \
            (((wr * 64 + mm * 16 + lr) * 128 + ((S0) + s) * 32 + lg * 8) ^ xr));      \
    _Pragma("unroll")                                                                 \
    for (int nn = 0; nn < 4; ++nn)                                                    \
      _Pragma("unroll")                                                               \
      for (int s = 0; s < 2; ++s)                                                     \
        bS[nn][s] = *(const long*)(Lb +                                               \
            (((wc * 64 + nn * 16 + lr) * 128 + ((S0) + s) * 32 + lg * 8) ^ xr));      \
  }
#define MFMA2()                                                                       \
  {                                                                                   \
    _Pragma("unroll")                                                                 \
    for (int s = 0; s < 2; ++s)                                                       \
      _Pragma("unroll")                                                               \
      for (int mm = 0; mm < 4; ++mm)                                                  \
        _Pragma("unroll")                                                             \
        for (int nn = 0; nn < 4; ++nn)                                                \
          acc[mm][nn] = __builtin_amdgcn_mfma_f32_16x16x32_fp8_fp8(                   \
              aS[mm][s], bS[nn][s], acc[mm][nn], 0, 0, 0);                            \
  }

// MODE 0 (t=0..5): stage A(t+1)->Ab + B(t+2)->Lb, vmcnt(4)  [drains B(t+1)+A(t+1),
//   keeps B(t+2) in flight — counted, no drain]. MODE 1 (t=6): stage A(7), vmcnt(0).
// MODE 2 (t=7): no stage, no barriers (synced at t=6 drain).
template<int MODE>
__device__ __forceinline__ void ktile(int t, char* La, char* Lb,
    const char* gA, const char* gB, int tid, int lane, int wr, int wc,
    long (&aS)[4][2], long (&bS)[4][2], f32x4 (&acc)[4][4]) {
  const int lr = lane & 15, lg = lane >> 4;
  const int xr = (lane & 7) << 4;
  READ_AB(0);
  __builtin_amdgcn_s_setprio(1); MFMA2(); __builtin_amdgcn_s_setprio(0);
  READ_AB(2);
  if constexpr (MODE < 2) {
    barf();                                   // all waves' tile-t reads precede stages
    stage_chunk(La, gA, t + 1, tid);          // A single-buffer, 1-ahead
    if constexpr (MODE == 0) {
      stage_chunk(Lb, gB, t + 2, tid);        // B double-buffer, 2-ahead (same parity)
      vmwait<4>();
    } else {
      vmwait<0>();                            // tail: A(7)+B(7) complete
    }
    barf();
  }
  __builtin_amdgcn_s_setprio(1); MFMA2(); __builtin_amdgcn_s_setprio(0);
}

extern "C" __global__ __launch_bounds__(256)
void koleo_grammax(const char* __restrict__ xq, unsigned* __restrict__ maxenc) {
  __shared__ char lds[49152];   // A 16KB + B 2x16KB -> 3 blocks/CU

  const int tid  = threadIdx.x;
  const int lane = tid & 63;
  const int wid  = tid >> 6;
  const int wr   = wid >> 1;     // 0..1: rows wr*64..+63
  const int wc   = wid & 1;      // 0..1: cols wc*64..+63
  const int lr   = lane & 15;
  const int lg   = lane >> 4;

  // XCD swizzle: XCD x gets sbid range [x*260, (x+1)*260) (2080 % 8 == 0)
  const int sbid = (blockIdx.x % 8) * (NBLK / 8) + blockIdx.x / 8;

  // Supertile order: 64x64 tile-triangle partitioned into 16x16-tile supertiles.
  // Per-XCD 260-block share touches ~32 row/col tiles = 4MB (fits per-XCD L2).
  int ti, tj;
  {
    const int SC[11] = {0, 136, 392, 648, 904, 1040, 1296, 1552, 1688, 1944, 2080};
    const int SI[10] = {0, 0, 0, 0, 1, 1, 1, 2, 2, 3};
    const int SJ[10] = {0, 1, 2, 3, 1, 2, 3, 2, 3, 3};
    int st = 0;
#pragma unroll
    for (int k = 1; k < 10; ++k) st += (sbid >= SC[k]);
    const int local = sbid - SC[st];
    const int I = SI[st], J = SJ[st];
    if (I == J) {            // diagonal supertile: 16-row upper triangle (136 blocks)
      int i = 0;
      while ((i + 1) * 16 - ((i + 1) * i) / 2 <= local) ++i;
      const int j = i + (local - (i * 16 - (i * (i - 1)) / 2));
      ti = I * 16 + i; tj = J * 16 + j;
    } else {                 // full 16x16 supertile (256 blocks)
      ti = I * 16 + local / 16; tj = J * 16 + local % 16;
    }
  }

  const int rowBase = ti * BM;
  const int colBase = tj * BM;
  const bool diag = (ti == tj);

  const char* gA = xq + (size_t)rowBase * 1024;
  const char* gB = xq + (size_t)colBase * 1024;
  char* Ab = lds;
  char* B0 = lds + 16384;
  char* B1 = lds + 32768;

  f32x4 acc[4][4] = {};
  long  aS[4][2];
  long  bS[4][2];

  // prologue: A(0)->Ab, B(0)->B0, B(1)->B1; vmcnt(4) = A(0),B(0) done, B(1) in flight
  stage_chunk(Ab, gA, 0, tid);
  stage_chunk(B0, gB, 0, tid);
  stage_chunk(B1, gB, 1, tid);
  vmwait<4>();
  barf();

#pragma unroll 1
  for (int t = 0; t < 6; ++t)
    ktile<0>(t, Ab, (t & 1) ? B1 : B0, gA, gB, tid, lane, wr, wc, aS, bS, acc);
  ktile<1>(6, Ab, B0, gA, gB, tid, lane, wr, wc, aS, bS, acc);
  ktile<2>(7, Ab, B1, gA, gB, tid, lane, wr, wc, aS, bS, acc);

  // ---- epilogue: per-row / per-col max with diagonal mask (16x16 C/D layout, proven) ----
  __syncthreads();
  unsigned* smaxr = (unsigned*)lds;           // [128]
  unsigned* smaxc = (unsigned*)(lds + 512);   // [128]
  if (tid < 128) { smaxr[tid] = 0u; smaxc[tid] = 0u; }
  __syncthreads();

#pragma unroll
  for (int m = 0; m < 4; ++m) {
#pragma unroll
    for (int rr = 0; rr < 4; ++rr) {
      const int lrow = wr * 64 + m * 16 + lg * 4 + rr;  // C/D: row=(lane>>4)*4+reg
      const int grow = rowBase + lrow;
      float mx = -2.0f;
#pragma unroll
      for (int n = 0; n < 4; ++n) {
        float v = acc[m][n][rr];
        const int gcol = colBase + wc * 64 + n * 16 + lr;  // C/D: col=lane&15
        if (grow == gcol) v = -2.0f;                        // mask self-similarity
        mx = fmaxf(mx, v);
      }
#pragma unroll
      for (int off = 1; off < 16; off <<= 1) mx = fmaxf(mx, __shfl_xor(mx, off));
      if (lr == 0) atomicMax(&smaxr[lrow], encf(mx));
    }
  }
  if (!diag) {  // symmetric fold: col j's max over this block's rows
#pragma unroll
    for (int n = 0; n < 4; ++n) {
      const int lcol = wc * 64 + n * 16 + lr;
      float mx = -2.0f;
#pragma unroll
      for (int m = 0; m < 4; ++m)
#pragma unroll
        for (int rr = 0; rr < 4; ++rr) mx = fmaxf(mx, acc[m][n][rr]);
      mx = fmaxf(mx, __shfl_xor(mx, 16));
      mx = fmaxf(mx, __shfl_xor(mx, 32));
      if (lg == 0) atomicMax(&smaxc[lcol], encf(mx));
    }
  }
  __syncthreads();
  if (tid < 128) {
    atomicMax(&maxenc[rowBase + tid], smaxr[tid]);
    if (!diag) atomicMax(&maxenc[colBase + tid], smaxc[tid]);
  }
}

// ---------------- Kernel C: loss reduction ----------------
extern "C" __global__ __launch_bounds__(1024)
void koleo_loss(const unsigned* __restrict__ maxenc, float* __restrict__ out) {
  const int tid = threadIdx.x;
  float sum = 0.0f;
#pragma unroll
  for (int i = tid; i < NROWS; i += 1024) {
    const unsigned u    = maxenc[i];
    const unsigned bits = (u & 0x80000000u) ? (u & 0x7FFFFFFFu) : ~u;
    const float m = __uint_as_float(bits);
    const float d = sqrtf(fmaxf(2.0f - 2.0f * m, 0.0f)) + EPSF;  // ||x_i - x_nn|| + eps
    sum += logf(d + EPSF);
  }
#pragma unroll
  for (int off = 32; off > 0; off >>= 1) sum += __shfl_down(sum, off);
  __shared__ float wsum[16];
  if ((tid & 63) == 0) wsum[tid >> 6] = sum;
  __syncthreads();
  if (tid == 0) {
    float t = 0.0f;
#pragma unroll
    for (int w = 0; w < 16; ++w) t += wsum[w];
    out[0] = -t / (float)NROWS;
  }
}

extern "C" void kernel_launch(void* const* d_in, const int* in_sizes, int n_in,
                              void* d_out, int out_size, void* d_ws, size_t ws_size,
                              hipStream_t stream) {
  const float* in = (const float*)d_in[0];
  char* xq         = (char*)d_ws;                                        // 8 MB fp8 x
  unsigned* maxenc = (unsigned*)((char*)d_ws + (size_t)NROWS * DIM);     // 32 KB
  float* out = (float*)d_out;

  hipLaunchKernelGGL(koleo_norm,    dim3(NROWS), dim3(256),  0, stream, in, (int*)xq, maxenc);
  hipLaunchKernelGGL(koleo_grammax, dim3(NBLK),  dim3(256),  0, stream, xq, maxenc);
  hipLaunchKernelGGL(koleo_loss,    dim3(1),     dim3(1024), 0, stream, maxenc, out);
}